// Round 1
// baseline (261.711 us; speedup 1.0000x reference)
//
#include <hip/hip_runtime.h>
#include <hip/hip_bf16.h>
#include <math.h>

#define BB 8
#define CC 256
#define HH 128
#define WW 128
#define NN 4096
#define EE 128

// ---- workspace layout (bytes) ----
#define WT_OFF   0                              // float[CC*EE]           = 128 KiB
#define BASE_OFF 131072                         // int[BB*NN]             = 128 KiB
#define WGT_OFF  262144                         // float4[BB*NN]          = 512 KiB
#define DESC_OFF 786432                         // float[BB*CC*NN]        = 32 MiB
#define WS_NEED  (786432ull + (unsigned long long)BB*CC*NN*4ull)

// Per-point precompute: base index (always in-bounds so base..base+WW+1 valid)
// + 4 bilinear weights with zero-padding baked in via separable OOB remap.
__global__ void coef_kernel(const float* __restrict__ kpts,
                            int* __restrict__ baseb, float4* __restrict__ wgt) {
  int i = blockIdx.x * blockDim.x + threadIdx.x;  // 0..BB*NN-1
  float kx = kpts[2 * i], ky = kpts[2 * i + 1];
  float ix = (kx + 1.f) * (WW * 0.5f) - 0.5f;
  float iy = (ky + 1.f) * (HH * 0.5f) - 0.5f;
  float x0f = floorf(ix), y0f = floorf(iy);
  float wx = ix - x0f, wy = iy - y0f;
  int x0 = (int)x0f, y0 = (int)y0f;
  float ax0 = (x0 >= 0 && x0 < WW) ? (1.f - wx) : 0.f;
  float ax1 = (x0 + 1 >= 0 && x0 + 1 < WW) ? wx : 0.f;
  float ay0 = (y0 >= 0 && y0 < HH) ? (1.f - wy) : 0.f;
  float ay1 = (y0 + 1 >= 0 && y0 + 1 < HH) ? wy : 0.f;
  int bx = min(max(x0, 0), WW - 2);
  int by = min(max(y0, 0), HH - 2);
  float a0 = 0.f, a1 = 0.f, c0 = 0.f, c1 = 0.f;
  if (x0 == bx) a0 += ax0; else if (x0 == bx + 1) a1 += ax0;
  if (x0 + 1 == bx) a0 += ax1; else if (x0 + 1 == bx + 1) a1 += ax1;
  if (y0 == by) c0 += ay0; else if (y0 == by + 1) c1 += ay0;
  if (y0 + 1 == by) c0 += ay1; else if (y0 + 1 == by + 1) c1 += ay1;
  baseb[i] = by * WW + bx;
  wgt[i] = make_float4(a0 * c0, a1 * c0, a0 * c1, a1 * c1);
}

// W[E][C] -> Wt[C][E] so GEMM LDS staging is coalesced + conflict-free.
__global__ void wtrans_kernel(const float* __restrict__ W, float* __restrict__ Wt) {
  int i = blockIdx.x * blockDim.x + threadIdx.x;  // 0..CC*EE-1
  int c = i >> 7, e = i & (EE - 1);
  Wt[i] = W[e * CC + c];
}

// One block per (b,c) plane: stage 64 KiB plane to LDS (coalesced),
// then random gathers hit LDS (2-way conflicts ~free) instead of L2/HBM lines.
__global__ __launch_bounds__(256) void gather_kernel(
    const float* __restrict__ x, const int* __restrict__ baseb,
    const float4* __restrict__ wgt, float* __restrict__ desc) {
  __shared__ float plane[HH * WW];  // 64 KiB -> 2 blocks/CU
  int blk = blockIdx.x;             // b*CC + c
  int b = blk >> 8;
  const float4* s4 = (const float4*)(x + ((size_t)blk << 14));
  float4* p4 = (float4*)plane;
  for (int i = threadIdx.x; i < (HH * WW / 4); i += 256) p4[i] = s4[i];
  __syncthreads();
  const int* bb = baseb + b * NN;
  const float4* wb = wgt + b * NN;
  float* dst = desc + ((size_t)blk << 12);  // desc[b][c][n]
  for (int n = threadIdx.x; n < NN; n += 256) {
    int base = bb[n];
    float4 w = wb[n];
    float v = plane[base] * w.x + plane[base + 1] * w.y
            + plane[base + WW] * w.z + plane[base + WW + 1] * w.w;
    dst[n] = v;
  }
}

// out[b,n,e] = normalize_e( sum_c W[e,c]*desc[b,c,n] + bias[e] )
// Tile: 128 n x 128 e per block, 8e x 8n per thread (64 acc regs).
__global__ __launch_bounds__(256) void gemm_norm_kernel(
    const float* __restrict__ desc, const float* __restrict__ Wt,
    const float* __restrict__ bias, float* __restrict__ out) {
  __shared__ float4 A4s[32 * 32];  // [cc][n/4]  16 KiB
  __shared__ float4 W4s[32 * 32];  // [cc][e/4]  16 KiB
  int t = threadIdx.x;
  int blk = blockIdx.x;            // b*32 + ntile
  int b = blk >> 5;
  int n0 = (blk & 31) << 7;
  int te = t & 15, tn = t >> 4;    // e = te*8+j, n = n0 + tn*8+k
  float acc[8][8];
#pragma unroll
  for (int j = 0; j < 8; ++j)
#pragma unroll
    for (int k = 0; k < 8; ++k) acc[j][k] = 0.f;
  const float4* wt4 = (const float4*)Wt;
  const float4* d4 = (const float4*)desc;
  for (int cb = 0; cb < CC; cb += 32) {
    __syncthreads();
    int base4 = (b * CC + cb) * (NN / 4) + (n0 >> 2);
#pragma unroll
    for (int p = 0; p < 4; ++p) {
      int q = t + 256 * p;               // 0..1023
      int cc = q >> 5, ii = q & 31;
      A4s[q] = d4[base4 + cc * (NN / 4) + ii];   // coalesced, row stride 1024 f4
      W4s[q] = wt4[(cb + cc) * (EE / 4) + ii];
    }
    __syncthreads();
    for (int cc = 0; cc < 32; ++cc) {
      float4 a0 = A4s[cc * 32 + tn * 2];
      float4 a1 = A4s[cc * 32 + tn * 2 + 1];
      float4 w0 = W4s[cc * 32 + te * 2];
      float4 w1 = W4s[cc * 32 + te * 2 + 1];
      float av[8] = {a0.x, a0.y, a0.z, a0.w, a1.x, a1.y, a1.z, a1.w};
      float wv[8] = {w0.x, w0.y, w0.z, w0.w, w1.x, w1.y, w1.z, w1.w};
#pragma unroll
      for (int j = 0; j < 8; ++j)
#pragma unroll
        for (int k = 0; k < 8; ++k) acc[j][k] += wv[j] * av[k];
    }
  }
  float4 bi0 = *(const float4*)&bias[te * 8];
  float4 bi1 = *(const float4*)&bias[te * 8 + 4];
  float bv[8] = {bi0.x, bi0.y, bi0.z, bi0.w, bi1.x, bi1.y, bi1.z, bi1.w};
#pragma unroll
  for (int j = 0; j < 8; ++j)
#pragma unroll
    for (int k = 0; k < 8; ++k) acc[j][k] += bv[j];
  float4* out4 = (float4*)out;
#pragma unroll
  for (int k = 0; k < 8; ++k) {
    float s = 0.f;
#pragma unroll
    for (int j = 0; j < 8; ++j) s += acc[j][k] * acc[j][k];
    // reduce over the 16 te-lanes (all share tn): masks 1,2,4,8
    s += __shfl_xor(s, 1); s += __shfl_xor(s, 2);
    s += __shfl_xor(s, 4); s += __shfl_xor(s, 8);
    float inv = 1.f / fmaxf(sqrtf(s), 1e-12f);
    int n = n0 + tn * 8 + k;
    size_t o = ((size_t)(b * NN + n) << 5) + te * 2;  // float4 units
    out4[o]     = make_float4(acc[0][k] * inv, acc[1][k] * inv, acc[2][k] * inv, acc[3][k] * inv);
    out4[o + 1] = make_float4(acc[4][k] * inv, acc[5][k] * inv, acc[6][k] * inv, acc[7][k] * inv);
  }
}

// Correctness fallback if ws_size is too small: one block per point.
__global__ __launch_bounds__(128) void fused_fallback(
    const float* __restrict__ x, const float* __restrict__ kpts,
    const float* __restrict__ W, const float* __restrict__ bias,
    float* __restrict__ out) {
  __shared__ float dsc[CC];
  __shared__ float sred[2];
  int blk = blockIdx.x;  // b*NN + n
  int b = blk >> 12;
  float kx = kpts[2 * blk], ky = kpts[2 * blk + 1];
  float ix = (kx + 1.f) * (WW * 0.5f) - 0.5f;
  float iy = (ky + 1.f) * (HH * 0.5f) - 0.5f;
  float x0f = floorf(ix), y0f = floorf(iy);
  float wx = ix - x0f, wy = iy - y0f;
  int x0 = (int)x0f, y0 = (int)y0f;
  float ax0 = (x0 >= 0 && x0 < WW) ? (1.f - wx) : 0.f;
  float ax1 = (x0 + 1 >= 0 && x0 + 1 < WW) ? wx : 0.f;
  float ay0 = (y0 >= 0 && y0 < HH) ? (1.f - wy) : 0.f;
  float ay1 = (y0 + 1 >= 0 && y0 + 1 < HH) ? wy : 0.f;
  int bx = min(max(x0, 0), WW - 2);
  int by = min(max(y0, 0), HH - 2);
  float a0 = 0.f, a1 = 0.f, r0 = 0.f, r1 = 0.f;
  if (x0 == bx) a0 += ax0; else if (x0 == bx + 1) a1 += ax0;
  if (x0 + 1 == bx) a0 += ax1; else if (x0 + 1 == bx + 1) a1 += ax1;
  if (y0 == by) r0 += ay0; else if (y0 == by + 1) r1 += ay0;
  if (y0 + 1 == by) r0 += ay1; else if (y0 + 1 == by + 1) r1 += ay1;
  int base = by * WW + bx;
  float w00 = a0 * r0, w10 = a1 * r0, w01 = a0 * r1, w11 = a1 * r1;
  int t = threadIdx.x;
  const float* src = x + ((size_t)b << 22);
  for (int c = t; c < CC; c += 128) {
    const float* p = src + ((size_t)c << 14);
    dsc[c] = p[base] * w00 + p[base + 1] * w10 + p[base + WW] * w01 + p[base + WW + 1] * w11;
  }
  __syncthreads();
  float acc = bias[t];
  const float* wr = W + t * CC;
  for (int c = 0; c < CC; ++c) acc += wr[c] * dsc[c];
  float s = acc * acc;
  for (int m = 1; m < 64; m <<= 1) s += __shfl_xor(s, m);
  if ((t & 63) == 0) sred[t >> 6] = s;
  __syncthreads();
  float tot = sred[0] + sred[1];
  float inv = 1.f / fmaxf(sqrtf(tot), 1e-12f);
  out[((size_t)blk << 7) + t] = acc * inv;
}

extern "C" void kernel_launch(void* const* d_in, const int* in_sizes, int n_in,
                              void* d_out, int out_size, void* d_ws, size_t ws_size,
                              hipStream_t stream) {
  const float* x    = (const float*)d_in[0];
  const float* kpts = (const float*)d_in[1];
  const float* W    = (const float*)d_in[2];
  const float* bias = (const float*)d_in[3];
  float* out = (float*)d_out;
  if (ws_size >= WS_NEED) {
    char* ws = (char*)d_ws;
    float* Wt    = (float*)(ws + WT_OFF);
    int* baseb   = (int*)(ws + BASE_OFF);
    float4* wgt  = (float4*)(ws + WGT_OFF);
    float* desc  = (float*)(ws + DESC_OFF);
    coef_kernel<<<BB * NN / 128, 128, 0, stream>>>(kpts, baseb, wgt);
    wtrans_kernel<<<CC * EE / 256, 256, 0, stream>>>(W, Wt);
    gather_kernel<<<BB * CC, 256, 0, stream>>>(x, baseb, wgt, desc);
    gemm_norm_kernel<<<BB * (NN / 128), 256, 0, stream>>>(desc, Wt, bias, out);
  } else {
    fused_fallback<<<BB * NN, 128, 0, stream>>>(x, kpts, W, bias, out);
  }
}

// Round 2
// 233.055 us; speedup vs baseline: 1.1230x; 1.1230x over previous
//
#include <hip/hip_runtime.h>
#include <hip/hip_bf16.h>
#include <math.h>

#define BB 8
#define CC 256
#define HH 128
#define WW 128
#define NN 4096
#define EE 128

// ---- workspace layout (bytes) ----
#define WT_OFF   0                              // float[CC*EE]           = 128 KiB
#define BASE_OFF 131072                         // int[BB*NN]             = 128 KiB
#define WGT_OFF  262144                         // float4[BB*NN]          = 512 KiB
#define DESC_OFF 786432                         // float[BB*CC*NN]        = 32 MiB
#define WS_NEED  (786432ull + (unsigned long long)BB*CC*NN*4ull)

// Fused: per-point bilinear coefs (32768 points) + W transpose (32768 elems).
__global__ __launch_bounds__(256) void prep_kernel(
    const float* __restrict__ kpts, const float* __restrict__ W,
    int* __restrict__ baseb, float4* __restrict__ wgt, float* __restrict__ Wt) {
  int i = blockIdx.x * blockDim.x + threadIdx.x;  // 0..32767
  // --- W transpose: Wt[c][e] = W[e][c] ---
  int c = i >> 7, e = i & (EE - 1);
  Wt[i] = W[e * CC + c];
  // --- bilinear coefs, zero-padding baked in via separable OOB remap ---
  float kx = kpts[2 * i], ky = kpts[2 * i + 1];
  float ix = (kx + 1.f) * (WW * 0.5f) - 0.5f;
  float iy = (ky + 1.f) * (HH * 0.5f) - 0.5f;
  float x0f = floorf(ix), y0f = floorf(iy);
  float wx = ix - x0f, wy = iy - y0f;
  int x0 = (int)x0f, y0 = (int)y0f;
  float ax0 = (x0 >= 0 && x0 < WW) ? (1.f - wx) : 0.f;
  float ax1 = (x0 + 1 >= 0 && x0 + 1 < WW) ? wx : 0.f;
  float ay0 = (y0 >= 0 && y0 < HH) ? (1.f - wy) : 0.f;
  float ay1 = (y0 + 1 >= 0 && y0 + 1 < HH) ? wy : 0.f;
  int bx = min(max(x0, 0), WW - 2);
  int by = min(max(y0, 0), HH - 2);
  float a0 = 0.f, a1 = 0.f, c0 = 0.f, c1 = 0.f;
  if (x0 == bx) a0 += ax0; else if (x0 == bx + 1) a1 += ax0;
  if (x0 + 1 == bx) a0 += ax1; else if (x0 + 1 == bx + 1) a1 += ax1;
  if (y0 == by) c0 += ay0; else if (y0 == by + 1) c1 += ay0;
  if (y0 + 1 == by) c0 += ay1; else if (y0 + 1 == by + 1) c1 += ay1;
  baseb[i] = by * WW + bx;
  wgt[i] = make_float4(a0 * c0, a1 * c0, a0 * c1, a1 * c1);
}

// One block per (b,c) plane: stage 64 KiB plane to LDS (coalesced),
// then random gathers hit LDS. 512 thr = 8 waves; 2 blocks/CU = 16 waves/CU.
__global__ __launch_bounds__(512) void gather_kernel(
    const float* __restrict__ x, const int* __restrict__ baseb,
    const float4* __restrict__ wgt, float* __restrict__ desc) {
  __shared__ float plane[HH * WW];  // 64 KiB
  int blk = blockIdx.x;             // b*CC + c
  int b = blk >> 8;
  int t = threadIdx.x;
  const float4* s4 = (const float4*)(x + ((size_t)blk << 14));
  float4* p4 = (float4*)plane;
#pragma unroll
  for (int i = 0; i < 8; ++i) p4[t + 512 * i] = s4[t + 512 * i];
  __syncthreads();
  const int* bb = baseb + b * NN;
  const float4* wb = wgt + b * NN;
  float* dst = desc + ((size_t)blk << 12);  // desc[b][c][n]
#pragma unroll
  for (int i = 0; i < 8; ++i) {
    int n = t + 512 * i;
    int base = bb[n];
    float4 w = wb[n];
    dst[n] = plane[base] * w.x + plane[base + 1] * w.y
           + plane[base + WW] * w.z + plane[base + WW + 1] * w.w;
  }
}

// out[b,n,e] = normalize_e( sum_c Wt[c][e]*desc[b,c,n] + bias[e] )
// Tile 64n x 128e per block, 512 thr, 4e x 4n per thread. 512 blocks -> 2/CU.
__global__ __launch_bounds__(512) void gemm_norm_kernel(
    const float* __restrict__ desc, const float* __restrict__ Wt,
    const float* __restrict__ bias, float* __restrict__ out) {
  __shared__ float4 A4s[32 * 16];  // [cc][n/4]  8 KiB
  __shared__ float4 W4s[32 * 32];  // [cc][e/4] 16 KiB
  int t = threadIdx.x;
  int blk = blockIdx.x;            // b*64 + ntile
  int b = blk >> 6;
  int n0 = (blk & 63) << 6;
  int te = t & 31;                 // e = te*4
  int tn = t >> 5;                 // n = n0 + tn*4
  float acc[4][4];
#pragma unroll
  for (int j = 0; j < 4; ++j)
#pragma unroll
    for (int k = 0; k < 4; ++k) acc[j][k] = 0.f;
  const float4* wt4 = (const float4*)Wt;
  const float4* d4 = (const float4*)desc;
  for (int cb = 0; cb < CC; cb += 32) {
    __syncthreads();
    int base4 = (b * CC + cb) * (NN / 4) + (n0 >> 2);
    {  // A: 512 float4, one per thread (coalesced, 16 f4 per cc-row)
      int ccA = t >> 4, iiA = t & 15;
      A4s[t] = d4[base4 + ccA * (NN / 4) + iiA];
    }
#pragma unroll
    for (int p = 0; p < 2; ++p) {  // W: 1024 float4
      int q = t + 512 * p;
      int cc = q >> 5, ii = q & 31;
      W4s[q] = wt4[(cb + cc) * (EE / 4) + ii];
    }
    __syncthreads();
#pragma unroll
    for (int cc = 0; cc < 32; ++cc) {
      float4 a = A4s[cc * 16 + tn];   // wave-broadcast (2 addrs/wave)
      float4 w = W4s[cc * 32 + te];
      float av[4] = {a.x, a.y, a.z, a.w};
      float wv[4] = {w.x, w.y, w.z, w.w};
#pragma unroll
      for (int j = 0; j < 4; ++j)
#pragma unroll
        for (int k = 0; k < 4; ++k) acc[j][k] += wv[j] * av[k];
    }
  }
  float4 bi = ((const float4*)bias)[te];
  float bv[4] = {bi.x, bi.y, bi.z, bi.w};
#pragma unroll
  for (int j = 0; j < 4; ++j)
#pragma unroll
    for (int k = 0; k < 4; ++k) acc[j][k] += bv[j];
  float4* out4 = (float4*)out;
#pragma unroll
  for (int k = 0; k < 4; ++k) {
    float s = 0.f;
#pragma unroll
    for (int j = 0; j < 4; ++j) s += acc[j][k] * acc[j][k];
    // reduce over 32 te-lanes (same tn): masks 1,2,4,8,16 stay in 32-lane half
    s += __shfl_xor(s, 1); s += __shfl_xor(s, 2); s += __shfl_xor(s, 4);
    s += __shfl_xor(s, 8); s += __shfl_xor(s, 16);
    float inv = 1.f / fmaxf(sqrtf(s), 1e-12f);
    int n = n0 + tn * 4 + k;
    out4[((size_t)(b * NN + n) << 5) + te] =
        make_float4(acc[0][k] * inv, acc[1][k] * inv, acc[2][k] * inv, acc[3][k] * inv);
  }
}

// Correctness fallback if ws_size is too small: one block per point.
__global__ __launch_bounds__(128) void fused_fallback(
    const float* __restrict__ x, const float* __restrict__ kpts,
    const float* __restrict__ W, const float* __restrict__ bias,
    float* __restrict__ out) {
  __shared__ float dsc[CC];
  __shared__ float sred[2];
  int blk = blockIdx.x;  // b*NN + n
  int b = blk >> 12;
  float kx = kpts[2 * blk], ky = kpts[2 * blk + 1];
  float ix = (kx + 1.f) * (WW * 0.5f) - 0.5f;
  float iy = (ky + 1.f) * (HH * 0.5f) - 0.5f;
  float x0f = floorf(ix), y0f = floorf(iy);
  float wx = ix - x0f, wy = iy - y0f;
  int x0 = (int)x0f, y0 = (int)y0f;
  float ax0 = (x0 >= 0 && x0 < WW) ? (1.f - wx) : 0.f;
  float ax1 = (x0 + 1 >= 0 && x0 + 1 < WW) ? wx : 0.f;
  float ay0 = (y0 >= 0 && y0 < HH) ? (1.f - wy) : 0.f;
  float ay1 = (y0 + 1 >= 0 && y0 + 1 < HH) ? wy : 0.f;
  int bx = min(max(x0, 0), WW - 2);
  int by = min(max(y0, 0), HH - 2);
  float a0 = 0.f, a1 = 0.f, r0 = 0.f, r1 = 0.f;
  if (x0 == bx) a0 += ax0; else if (x0 == bx + 1) a1 += ax0;
  if (x0 + 1 == bx) a0 += ax1; else if (x0 + 1 == bx + 1) a1 += ax1;
  if (y0 == by) r0 += ay0; else if (y0 == by + 1) r1 += ay0;
  if (y0 + 1 == by) r0 += ay1; else if (y0 + 1 == by + 1) r1 += ay1;
  int base = by * WW + bx;
  float w00 = a0 * r0, w10 = a1 * r0, w01 = a0 * r1, w11 = a1 * r1;
  int t = threadIdx.x;
  const float* src = x + ((size_t)b << 22);
  for (int c = t; c < CC; c += 128) {
    const float* p = src + ((size_t)c << 14);
    dsc[c] = p[base] * w00 + p[base + 1] * w10 + p[base + WW] * w01 + p[base + WW + 1] * w11;
  }
  __syncthreads();
  float acc = bias[t];
  const float* wr = W + t * CC;
  for (int c = 0; c < CC; ++c) acc += wr[c] * dsc[c];
  float s = acc * acc;
  for (int m = 1; m < 64; m <<= 1) s += __shfl_xor(s, m);
  if ((t & 63) == 0) sred[t >> 6] = s;
  __syncthreads();
  float tot = sred[0] + sred[1];
  float inv = 1.f / fmaxf(sqrtf(tot), 1e-12f);
  out[((size_t)blk << 7) + t] = acc * inv;
}

extern "C" void kernel_launch(void* const* d_in, const int* in_sizes, int n_in,
                              void* d_out, int out_size, void* d_ws, size_t ws_size,
                              hipStream_t stream) {
  const float* x    = (const float*)d_in[0];
  const float* kpts = (const float*)d_in[1];
  const float* W    = (const float*)d_in[2];
  const float* bias = (const float*)d_in[3];
  float* out = (float*)d_out;
  if (ws_size >= WS_NEED) {
    char* ws = (char*)d_ws;
    float* Wt    = (float*)(ws + WT_OFF);
    int* baseb   = (int*)(ws + BASE_OFF);
    float4* wgt  = (float4*)(ws + WGT_OFF);
    float* desc  = (float*)(ws + DESC_OFF);
    prep_kernel<<<BB * NN / 256, 256, 0, stream>>>(kpts, W, baseb, wgt, Wt);
    gather_kernel<<<BB * CC, 512, 0, stream>>>(x, baseb, wgt, desc);
    gemm_norm_kernel<<<BB * (NN / 64), 512, 0, stream>>>(desc, Wt, bias, out);
  } else {
    fused_fallback<<<BB * NN, 128, 0, stream>>>(x, kpts, W, bias, out);
  }
}

// Round 3
// 222.071 us; speedup vs baseline: 1.1785x; 1.0495x over previous
//
#include <hip/hip_runtime.h>
#include <hip/hip_bf16.h>
#include <math.h>

#define BB 8
#define CC 256
#define HH 128
#define WW 128
#define NN 4096
#define EE 128

typedef __bf16 bf16x8 __attribute__((ext_vector_type(8)));
typedef float f32x4 __attribute__((ext_vector_type(4)));

// ---- workspace layout (bytes) ----
#define WF_OFF    0          // __bf16[8][8][64][8]        = 64 KiB  (W, A-frag order)
#define BASE_OFF  65536      // int[BB*NN]                 = 128 KiB
#define WGT_OFF   196608     // float4[BB*NN]              = 512 KiB
#define DESCF_OFF 720896     // __bf16[BB][256][8][64][8]  = 16 MiB  (desc, B-frag order)
#define WS_NEED   (720896ull + 16777216ull)

// Fused per-point bilinear coefs + W -> bf16 A-fragment order.
// Wf[kstep][etile][lane][j] = W[etile*16 + (lane&15)][kstep*32 + (lane>>4)*8 + j]
__global__ __launch_bounds__(256) void prep_kernel(
    const float* __restrict__ kpts, const float* __restrict__ W,
    int* __restrict__ baseb, float4* __restrict__ wgt, __bf16* __restrict__ Wf) {
  int i = blockIdx.x * blockDim.x + threadIdx.x;  // 0..32767
  {
    int j = i & 7, lane = (i >> 3) & 63, etile = (i >> 9) & 7, kstep = (i >> 12) & 7;
    int e = etile * 16 + (lane & 15);
    int c = kstep * 32 + ((lane >> 4) << 3) + j;
    Wf[i] = (__bf16)W[e * CC + c];
  }
  // bilinear coefs; zero-padding baked in via separable OOB remap
  float kx = kpts[2 * i], ky = kpts[2 * i + 1];
  float ix = (kx + 1.f) * (WW * 0.5f) - 0.5f;
  float iy = (ky + 1.f) * (HH * 0.5f) - 0.5f;
  float x0f = floorf(ix), y0f = floorf(iy);
  float wx = ix - x0f, wy = iy - y0f;
  int x0 = (int)x0f, y0 = (int)y0f;
  float ax0 = (x0 >= 0 && x0 < WW) ? (1.f - wx) : 0.f;
  float ax1 = (x0 + 1 >= 0 && x0 + 1 < WW) ? wx : 0.f;
  float ay0 = (y0 >= 0 && y0 < HH) ? (1.f - wy) : 0.f;
  float ay1 = (y0 + 1 >= 0 && y0 + 1 < HH) ? wy : 0.f;
  int bx = min(max(x0, 0), WW - 2);
  int by = min(max(y0, 0), HH - 2);
  float a0 = 0.f, a1 = 0.f, c0 = 0.f, c1 = 0.f;
  if (x0 == bx) a0 += ax0; else if (x0 == bx + 1) a1 += ax0;
  if (x0 + 1 == bx) a0 += ax1; else if (x0 + 1 == bx + 1) a1 += ax1;
  if (y0 == by) c0 += ay0; else if (y0 == by + 1) c1 += ay0;
  if (y0 + 1 == by) c0 += ay1; else if (y0 + 1 == by + 1) c1 += ay1;
  baseb[i] = by * WW + bx;
  wgt[i] = make_float4(a0 * c0, a1 * c0, a0 * c1, a1 * c1);
}

// One block per (b,c) plane: stage 64 KiB plane to LDS (coalesced),
// random gathers hit LDS, result written bf16 in MFMA B-fragment order:
// descf[b][n>>4][c>>5][quad*16 + (n&15)][c&7],  quad = (c>>3)&3.
__global__ __launch_bounds__(512) void gather_kernel(
    const float* __restrict__ x, const int* __restrict__ baseb,
    const float4* __restrict__ wgt, __bf16* __restrict__ descf) {
  __shared__ float plane[HH * WW];  // 64 KiB
  int blk = blockIdx.x;             // b*CC + c
  int b = blk >> 8, c = blk & 255;
  int t = threadIdx.x;
  const float4* s4 = (const float4*)(x + ((size_t)blk << 14));
  float4* p4 = (float4*)plane;
#pragma unroll
  for (int i = 0; i < 8; ++i) p4[t + 512 * i] = s4[t + 512 * i];
  __syncthreads();
  const int* bb = baseb + b * NN;
  const float4* wb = wgt + b * NN;
  __bf16* dst = descf + ((b << 20) + ((c >> 5) << 9) + (((c >> 3) & 3) << 7) + (c & 7));
#pragma unroll
  for (int i = 0; i < 8; ++i) {
    int n = t + 512 * i;
    int base = bb[n];
    float4 w = wb[n];
    float v = plane[base] * w.x + plane[base + 1] * w.y
            + plane[base + WW] * w.z + plane[base + WW + 1] * w.w;
    dst[((n >> 4) << 12) + ((n & 15) << 3)] = (__bf16)v;
  }
}

// MFMA GEMM + bias + L2-normalize.
// 512 blocks x 256 thr (4 waves). Wave = one ntile (16 n) x full 128 e.
// A (W) frags from LDS (staged once, conflict-free b128); B (desc) frags
// straight from global, all 8 prefetched; no barriers in K-loop.
__global__ __launch_bounds__(256) void gemm_norm_kernel(
    const __bf16* __restrict__ descf, const __bf16* __restrict__ Wf,
    const float* __restrict__ bias, float* __restrict__ out) {
  __shared__ __bf16 wlds[8 * 8 * 64 * 8];  // 64 KiB
  int t = threadIdx.x;
  {
    const float4* src = (const float4*)Wf;
    float4* d = (float4*)wlds;
#pragma unroll
    for (int i = 0; i < 16; ++i) d[t + 256 * i] = src[t + 256 * i];
  }
  __syncthreads();
  int blk = blockIdx.x;  // b*64 + nblk
  int b = blk >> 6;
  int wave = t >> 6, lane = t & 63;
  int ntile = ((blk & 63) << 2) + wave;  // 0..255 within b
  const bf16x8* bsrc =
      (const bf16x8*)(descf + ((size_t)b << 20) + ((size_t)ntile << 12));
  bf16x8 bfrag[8];
#pragma unroll
  for (int k = 0; k < 8; ++k) bfrag[k] = bsrc[k * 64 + lane];  // prefetch all B
  const bf16x8* alds = (const bf16x8*)wlds;
  f32x4 acc[8];
#pragma unroll
  for (int e = 0; e < 8; ++e) acc[e] = (f32x4)(0.f);
#pragma unroll
  for (int k = 0; k < 8; ++k) {
#pragma unroll
    for (int e = 0; e < 8; ++e) {
      bf16x8 a = alds[(k * 8 + e) * 64 + lane];
      acc[e] = __builtin_amdgcn_mfma_f32_16x16x32_bf16(a, bfrag[k], acc[e], 0, 0, 0);
    }
  }
  // epilogue: D col=lane&15 -> n, row=quad*4+reg -> e (+16*etile)
  int quad = lane >> 4, col = lane & 15;
  int n = ntile * 16 + col;
  float s = 0.f;
  float4 av[8];
#pragma unroll
  for (int e = 0; e < 8; ++e) {
    float4 bi = *(const float4*)(bias + e * 16 + quad * 4);
    float4 v = make_float4(acc[e][0] + bi.x, acc[e][1] + bi.y,
                           acc[e][2] + bi.z, acc[e][3] + bi.w);
    av[e] = v;
    s += v.x * v.x + v.y * v.y + v.z * v.z + v.w * v.w;
  }
  s += __shfl_xor(s, 16);
  s += __shfl_xor(s, 32);
  float inv = 1.f / fmaxf(sqrtf(s), 1e-12f);
  float4* out4 = (float4*)out + (((size_t)(b * NN + n)) << 5) + quad;
#pragma unroll
  for (int e = 0; e < 8; ++e)
    out4[e * 4] = make_float4(av[e].x * inv, av[e].y * inv,
                              av[e].z * inv, av[e].w * inv);
}

// Correctness fallback if ws_size is too small: one block per point.
__global__ __launch_bounds__(128) void fused_fallback(
    const float* __restrict__ x, const float* __restrict__ kpts,
    const float* __restrict__ W, const float* __restrict__ bias,
    float* __restrict__ out) {
  __shared__ float dsc[CC];
  __shared__ float sred[2];
  int blk = blockIdx.x;  // b*NN + n
  int b = blk >> 12;
  float kx = kpts[2 * blk], ky = kpts[2 * blk + 1];
  float ix = (kx + 1.f) * (WW * 0.5f) - 0.5f;
  float iy = (ky + 1.f) * (HH * 0.5f) - 0.5f;
  float x0f = floorf(ix), y0f = floorf(iy);
  float wx = ix - x0f, wy = iy - y0f;
  int x0 = (int)x0f, y0 = (int)y0f;
  float ax0 = (x0 >= 0 && x0 < WW) ? (1.f - wx) : 0.f;
  float ax1 = (x0 + 1 >= 0 && x0 + 1 < WW) ? wx : 0.f;
  float ay0 = (y0 >= 0 && y0 < HH) ? (1.f - wy) : 0.f;
  float ay1 = (y0 + 1 >= 0 && y0 + 1 < HH) ? wy : 0.f;
  int bx = min(max(x0, 0), WW - 2);
  int by = min(max(y0, 0), HH - 2);
  float a0 = 0.f, a1 = 0.f, r0 = 0.f, r1 = 0.f;
  if (x0 == bx) a0 += ax0; else if (x0 == bx + 1) a1 += ax0;
  if (x0 + 1 == bx) a0 += ax1; else if (x0 + 1 == bx + 1) a1 += ax1;
  if (y0 == by) r0 += ay0; else if (y0 == by + 1) r1 += ay0;
  if (y0 + 1 == by) r0 += ay1; else if (y0 + 1 == by + 1) r1 += ay1;
  int base = by * WW + bx;
  float w00 = a0 * r0, w10 = a1 * r0, w01 = a0 * r1, w11 = a1 * r1;
  int t = threadIdx.x;
  const float* src = x + ((size_t)b << 22);
  for (int c = t; c < CC; c += 128) {
    const float* p = src + ((size_t)c << 14);
    dsc[c] = p[base] * w00 + p[base + 1] * w10 + p[base + WW] * w01 + p[base + WW + 1] * w11;
  }
  __syncthreads();
  float acc = bias[t];
  const float* wr = W + t * CC;
  for (int c = 0; c < CC; ++c) acc += wr[c] * dsc[c];
  float s = acc * acc;
  for (int m = 1; m < 64; m <<= 1) s += __shfl_xor(s, m);
  if ((t & 63) == 0) sred[t >> 6] = s;
  __syncthreads();
  float tot = sred[0] + sred[1];
  float inv = 1.f / fmaxf(sqrtf(tot), 1e-12f);
  out[((size_t)blk << 7) + t] = acc * inv;
}

extern "C" void kernel_launch(void* const* d_in, const int* in_sizes, int n_in,
                              void* d_out, int out_size, void* d_ws, size_t ws_size,
                              hipStream_t stream) {
  const float* x    = (const float*)d_in[0];
  const float* kpts = (const float*)d_in[1];
  const float* W    = (const float*)d_in[2];
  const float* bias = (const float*)d_in[3];
  float* out = (float*)d_out;
  if (ws_size >= WS_NEED) {
    char* ws = (char*)d_ws;
    __bf16* Wf    = (__bf16*)(ws + WF_OFF);
    int* baseb    = (int*)(ws + BASE_OFF);
    float4* wgt   = (float4*)(ws + WGT_OFF);
    __bf16* descf = (__bf16*)(ws + DESCF_OFF);
    prep_kernel<<<BB * NN / 256, 256, 0, stream>>>(kpts, W, baseb, wgt, Wf);
    gather_kernel<<<BB * CC, 512, 0, stream>>>(x, baseb, wgt, descf);
    gemm_norm_kernel<<<BB * (NN / 64), 256, 0, stream>>>(descf, Wf, bias, out);
  } else {
    fused_fallback<<<BB * NN, 128, 0, stream>>>(x, kpts, W, bias, out);
  }
}